// Round 4
// baseline (255.972 us; speedup 1.0000x reference)
//
#include <hip/hip_runtime.h>

// ---------------------------------------------------------------------------
// WindowedMSA: B=2, H=W=256, C=96, win=16, heads=4, hd=24
// FULLY FUSED: one kernel per window does qkv-proj + attention + LePE +
// out-proj. 8 waves/block (32 tokens per wave) for 16 waves/CU occupancy.
// x held in registers (6 bf16x8/lane); per-head Q in wave-private LDS
// (overlaid with P/O scratch), K, V^T in shared LDS. No global intermediates.
// ---------------------------------------------------------------------------

typedef __attribute__((ext_vector_type(8))) short bf16x8;
typedef __attribute__((ext_vector_type(4))) float f32x4;

#define MFMA(a, b, c) __builtin_amdgcn_mfma_f32_16x16x32_bf16(a, b, c, 0, 0, 0)

#if __has_builtin(__builtin_amdgcn_exp2f)
#define EXP2F(x) __builtin_amdgcn_exp2f(x)
#else
#define EXP2F(x) exp2f(x)
#endif

#define SCALE2 (0.20412414523193154f * 1.4426950408889634f)

// ws layout (bytes)
#define OFF_WT   0u           // ushort[288*96]   qkv_w^T bf16 (row=out-ch, k-contig)
#define OFF_B2   55296u       // float[288]       qkv bias (q entries pre-scaled)
#define OFF_WTO  56448u       // ushort[96*96]    out_w^T bf16 (+slack for lq=3 over-read)
// end ~76 KB

__device__ __forceinline__ unsigned short f2bf(float f) {
    union { float f; unsigned int u; } v; v.f = f;
    unsigned int u = v.u;
    return (unsigned short)((u + 0x7FFFu + ((u >> 16) & 1u)) >> 16);
}
__device__ __forceinline__ float bf2f(unsigned short h) {
    union { unsigned int u; float f; } v; v.u = ((unsigned int)h) << 16;
    return v.f;
}
__device__ __forceinline__ unsigned int pk2bf(float a, float b) {
#if __has_builtin(__builtin_amdgcn_cvt_pk_bf16_f32)
    auto p = __builtin_amdgcn_cvt_pk_bf16_f32(a, b);
    union { decltype(p) v; unsigned int u; } cv; cv.v = p;
    return cv.u;
#else
    return (unsigned int)f2bf(a) | ((unsigned int)f2bf(b) << 16);
#endif
}
__device__ __forceinline__ float frcp(float x) {
#if __has_builtin(__builtin_amdgcn_rcpf)
    return __builtin_amdgcn_rcpf(x);
#else
    return 1.0f / x;
#endif
}

// ---------------------------------------------------------------------------
// prep: transpose + bf16-cast weights, pre-scale q rows.
// ---------------------------------------------------------------------------
__global__ void prep_kernel(const float* __restrict__ qkv_w,
                            const float* __restrict__ qkv_b,
                            const float* __restrict__ out_w,
                            unsigned short* __restrict__ wt,
                            float* __restrict__ b2,
                            unsigned short* __restrict__ wto) {
    const int stride = gridDim.x * 256;
    int i0 = blockIdx.x * 256 + threadIdx.x;
    for (int i = i0; i < 288 * 96; i += stride) {
        const int c = i / 96, k = i % 96;
        float v = qkv_w[k * 288 + c];
        if ((c % 72) < 24) v *= SCALE2;
        wt[i] = f2bf(v);
    }
    for (int i = i0; i < 288; i += stride) {
        float v = qkv_b[i];
        if ((i % 72) < 24) v *= SCALE2;
        b2[i] = v;
    }
    for (int i = i0; i < 96 * 96; i += stride) {
        const int c = i / 96, k = i % 96;
        wto[i] = f2bf(out_w[k * 96 + c]);
    }
}

// ---------------------------------------------------------------------------
// Fused kernel: 1 block per window (grid 512), 512 threads (8 waves).
// Wave w owns tokens w*32..w*32+31 (token tiles w*2, w*2+1).
// LDS: ~49.7 KB -> 2 blocks/CU = 16 waves/CU.
// ---------------------------------------------------------------------------
__launch_bounds__(512, 4)
__global__ void fused_kernel(const float* __restrict__ x,
                             const unsigned short* __restrict__ wt,
                             const float* __restrict__ b2,
                             const float* __restrict__ pe_w,
                             const float* __restrict__ pe_b,
                             const unsigned short* __restrict__ wto,
                             const float* __restrict__ out_b,
                             float* __restrict__ out) {
    __shared__ unsigned short sK[256 * 24 + 8];     // 12304 B shared K (token-major)
    __shared__ unsigned short sVT[32 * 264];        // 16896 B V^T; row24=ones, 25..31 junk (contained)
    __shared__ unsigned short sPO[8 * 32 * 40];     // 20480 B per-wave Q / P / O overlay
    __shared__ float sPW[216];
    __shared__ float sPB[24];

    const int n = blockIdx.x, tid = threadIdx.x;
    const int w = tid >> 6, l = tid & 63;
    const int lm = l & 15, lq = l >> 4;
    const int bW = n >> 8, hy = (n >> 4) & 15, wx = n & 15;
    unsigned short* Pw = &sPO[w * 32 * 40];

    // ones row of sVT (denominator column), written once
    if (tid < 64) {
        ushort4 ones; ones.x = ones.y = ones.z = ones.w = (unsigned short)0x3F80;
        *(ushort4*)&sVT[24 * 264 + tid * 4] = ones;
    }

    // ---- x fragments for this wave's 2 token tiles, held in registers ----
    // token = w*32 + t4*16 + lm  ->  y = w*2 + t4, x = lm  (within window)
    bf16x8 zf[2][3];
#pragma unroll
    for (int t4 = 0; t4 < 2; t4++) {
        const int y = w * 2 + t4;
        const size_t grow = (size_t)((bW * 256 + hy * 16 + y) * 256 + wx * 16 + lm);
        const float* xr = x + grow * 96 + lq * 8;
#pragma unroll
        for (int ks = 0; ks < 3; ks++) {
            const float4 p0 = *(const float4*)(xr + ks * 32);
            const float4 p1 = *(const float4*)(xr + ks * 32 + 4);
            union { unsigned int u[4]; bf16x8 v; } cv;
            cv.u[0] = pk2bf(p0.x, p0.y); cv.u[1] = pk2bf(p0.z, p0.w);
            cv.u[2] = pk2bf(p1.x, p1.y); cv.u[3] = pk2bf(p1.z, p1.w);
            zf[t4][ks] = cv.v;
        }
    }

    f32x4 oacc[2][6];
#pragma unroll
    for (int b = 0; b < 2; b++)
#pragma unroll
        for (int nt = 0; nt < 6; nt++) oacc[b][nt] = (f32x4){0.f, 0.f, 0.f, 0.f};

    for (int h = 0; h < 4; h++) {
        __syncthreads();   // prev head's sK/sVT/sPW readers done

        // ---- Phase A: Q,K head h for this wave's tokens (out-ch rows of wt) ----
        // Output: col=lm -> token (w*32 + t4*16 + lm), row=r48=mt*16+lq*4 -> qkv ch.
        // r48<24 -> Q (wave-private overlay, pitch 40), else K (shared, pitch 24).
#pragma unroll
        for (int mt = 0; mt < 3; mt++) {
            bf16x8 af[3];
#pragma unroll
            for (int ks = 0; ks < 3; ks++)
                af[ks] = *(const bf16x8*)(wt + (h * 72 + mt * 16 + lm) * 96 + ks * 32 + lq * 8);
            const int r48 = mt * 16 + lq * 4;
            const float4 bias = *(const float4*)(b2 + h * 72 + r48);
#pragma unroll
            for (int t4 = 0; t4 < 2; t4++) {
                f32x4 acc = {0.f, 0.f, 0.f, 0.f};
#pragma unroll
                for (int ks = 0; ks < 3; ks++) acc = MFMA(af[ks], zf[t4][ks], acc);
                uint2 pk;
                pk.x = pk2bf(acc[0] + bias.x, acc[1] + bias.y);
                pk.y = pk2bf(acc[2] + bias.z, acc[3] + bias.w);
                const int tl = t4 * 16 + lm;           // local token 0..31
                if (r48 < 24) *(uint2*)&Pw[tl * 40 + r48] = pk;
                else          *(uint2*)&sK[(w * 32 + tl) * 24 + (r48 - 24)] = pk;
            }
        }

        // ---- Phase B: V^T head h for this wave's tokens ----
        // Output: col=lm -> ch (nv*16+lm), row=lq*4+r -> token within tile.
#pragma unroll
        for (int nv = 0; nv < 2; nv++) {
            const int ch = nv * 16 + lm;
            const int vrow = h * 72 + 48 + (ch < 24 ? ch : 23);
            bf16x8 bw[3];
#pragma unroll
            for (int ks = 0; ks < 3; ks++)
                bw[ks] = *(const bf16x8*)(wt + vrow * 96 + ks * 32 + lq * 8);
            const float bv = b2[vrow];
#pragma unroll
            for (int t4 = 0; t4 < 2; t4++) {
                f32x4 acc = {0.f, 0.f, 0.f, 0.f};
#pragma unroll
                for (int ks = 0; ks < 3; ks++) acc = MFMA(zf[t4][ks], bw[ks], acc);
                if (ch < 24) {
                    uint2 pk;
                    pk.x = pk2bf(acc[0] + bv, acc[1] + bv);
                    pk.y = pk2bf(acc[2] + bv, acc[3] + bv);
                    *(uint2*)&sVT[ch * 264 + w * 32 + t4 * 16 + lq * 4] = pk;
                }
            }
        }

        // LePE weights for head h
        for (int i = tid; i < 216; i += 512) sPW[i] = pe_w[(i / 24) * 96 + h * 24 + (i % 24)];
        if (tid < 24) sPB[tid] = pe_b[h * 24 + tid];

        __syncthreads();   // K / V^T / pe staged

        // ---- attention (all operands in LDS) ----
        // Q consumed into registers BEFORE first P write to the same region
        // (wave-private, DS in-order per wave => safe overlay).
        bf16x8 qf[2];
#pragma unroll
        for (int b = 0; b < 2; b++) {
            bf16x8 qv = *(const bf16x8*)&Pw[(b * 16 + lm) * 40 + lq * 8];
            if (lq == 3) qv = (bf16x8)(short)0;
            qf[b] = qv;
        }

        f32x4 oa[2][2];
#pragma unroll
        for (int b = 0; b < 2; b++)
#pragma unroll
            for (int c = 0; c < 2; c++) oa[b][c] = (f32x4){0.f, 0.f, 0.f, 0.f};

        for (int kc = 0; kc < 8; kc++) {
            bf16x8 kfc[2];
#pragma unroll
            for (int a = 0; a < 2; a++)
                kfc[a] = *(const bf16x8*)&sK[(kc * 32 + a * 16 + lm) * 24 + lq * 8];
#pragma unroll
            for (int a = 0; a < 2; a++) {
                f32x4 s[2];
#pragma unroll
                for (int b = 0; b < 2; b++)
                    s[b] = MFMA(kfc[a], qf[b], ((f32x4){0.f, 0.f, 0.f, 0.f}));
#pragma unroll
                for (int b = 0; b < 2; b++) {
                    uint2 pk;
                    pk.x = pk2bf(EXP2F(s[b][0]), EXP2F(s[b][1]));
                    pk.y = pk2bf(EXP2F(s[b][2]), EXP2F(s[b][3]));
                    *(uint2*)&Pw[(b * 16 + lm) * 40 + a * 16 + lq * 4] = pk;
                }
            }
            bf16x8 vb[2];
#pragma unroll
            for (int c = 0; c < 2; c++)
                vb[c] = *(const bf16x8*)&sVT[(c * 16 + lm) * 264 + kc * 32 + lq * 8];
#pragma unroll
            for (int b = 0; b < 2; b++) {
                const bf16x8 pa = *(const bf16x8*)&Pw[(b * 16 + lm) * 40 + lq * 8];
#pragma unroll
                for (int c = 0; c < 2; c++) oa[b][c] = MFMA(pa, vb[c], oa[b][c]);
            }
        }

        // ---- epilogue: denom, LePE (strip reads), O -> wave-private LDS ----
        if (l < 32) {   // zero O k-pad cols 24..31 of this wave's rows (after last P read)
            uint4 zz = {0u, 0u, 0u, 0u};
            *(uint4*)&Pw[l * 40 + 24] = zz;
        }
        float w9[2][9], pb2[2];
#pragma unroll
        for (int c = 0; c < 2; c++) {
            const int ch = c * 16 + lm;
            if (ch < 24) {
#pragma unroll
                for (int ta = 0; ta < 9; ta++) w9[c][ta] = sPW[ta * 24 + ch];
                pb2[c] = sPB[ch];
            }
        }
#pragma unroll
        for (int b = 0; b < 2; b++) {
            float rinv[4];
#pragma unroll
            for (int r = 0; r < 4; r++)
                rinv[r] = frcp(__shfl(oa[b][1][r], (l & 48) | 8, 64));
            const int y = w * 2 + b;     // all 16 tokens of this m-tile share y
            const int x0 = lq * 4;
#pragma unroll
            for (int c = 0; c < 2; c++) {
                const int ch = c * 16 + lm;
                if (ch < 24) {
                    float lep[4] = {pb2[c], pb2[c], pb2[c], pb2[c]};
                    const unsigned short* vbase = &sVT[ch * 264];
#pragma unroll
                    for (int dy = -1; dy <= 1; dy++) {
                        const int ny = y + dy;
                        if ((unsigned)ny > 15u) continue;
                        const unsigned short* vrow = vbase + ny * 16;
                        const float wl = w9[c][(dy + 1) * 3 + 0];
                        const float wm = w9[c][(dy + 1) * 3 + 1];
                        const float wr = w9[c][(dy + 1) * 3 + 2];
#pragma unroll
                        for (int d = -1; d <= 4; d++) {
                            const int xx = x0 + d;
                            if ((unsigned)xx > 15u) continue;
                            const float v = bf2f(vrow[xx]);
                            if (d - 1 >= 0 && d - 1 <= 3) lep[d - 1] = fmaf(v, wr, lep[d - 1]);
                            if (d >= 0 && d <= 3)         lep[d]     = fmaf(v, wm, lep[d]);
                            if (d + 1 <= 3)               lep[d + 1] = fmaf(v, wl, lep[d + 1]);
                        }
                    }
#pragma unroll
                    for (int r = 0; r < 4; r++) {
                        const float val = oa[b][c][r] * rinv[r] + lep[r];
                        Pw[(b * 16 + lq * 4 + r) * 40 + ch] = f2bf(val);
                    }
                }
            }
        }

        // ---- partial out-proj (wave-private, in-order DS => no barrier) ----
        bf16x8 aO[2];
#pragma unroll
        for (int b = 0; b < 2; b++)
            aO[b] = *(const bf16x8*)&Pw[(b * 16 + lm) * 40 + lq * 8];
#pragma unroll
        for (int nt = 0; nt < 6; nt++) {
            const bf16x8 bwf = *(const bf16x8*)(wto + (nt * 16 + lm) * 96 + h * 24 + lq * 8);
#pragma unroll
            for (int b = 0; b < 2; b++) oacc[b][nt] = MFMA(aO[b], bwf, oacc[b][nt]);
        }
    }

    // ---- final store with reverse window partition ----
#pragma unroll
    for (int nt = 0; nt < 6; nt++) {
        const float bias = out_b[nt * 16 + lm];
#pragma unroll
        for (int b = 0; b < 2; b++) {
#pragma unroll
            for (int r = 0; r < 4; r++) {
                const int t = w * 32 + b * 16 + lq * 4 + r;
                const size_t grow =
                    (size_t)((bW * 256 + hy * 16 + (t >> 4)) * 256 + wx * 16 + (t & 15));
                out[grow * 96 + nt * 16 + lm] = oacc[b][nt][r] + bias;
            }
        }
    }
}

extern "C" void kernel_launch(void* const* d_in, const int* in_sizes, int n_in,
                              void* d_out, int out_size, void* d_ws, size_t ws_size,
                              hipStream_t stream) {
    const float* x     = (const float*)d_in[0];
    const float* qkv_w = (const float*)d_in[1];
    const float* qkv_b = (const float*)d_in[2];
    const float* pe_w  = (const float*)d_in[3];
    const float* pe_b  = (const float*)d_in[4];
    const float* out_w = (const float*)d_in[5];
    const float* out_b = (const float*)d_in[6];
    float* out = (float*)d_out;

    char* ws = (char*)d_ws;
    unsigned short* wt  = (unsigned short*)(ws + OFF_WT);
    float*          b2  = (float*)(ws + OFF_B2);
    unsigned short* wto = (unsigned short*)(ws + OFF_WTO);

    prep_kernel<<<72, 256, 0, stream>>>(qkv_w, qkv_b, out_w, wt, b2, wto);
    fused_kernel<<<512, 512, 0, stream>>>(x, wt, b2, pe_w, pe_b, wto, out_b, out);
}

// Round 5
// 182.596 us; speedup vs baseline: 1.4018x; 1.4018x over previous
//
#include <hip/hip_runtime.h>

// ---------------------------------------------------------------------------
// WindowedMSA: B=2, H=W=256, C=96, win=16, heads=4, hd=24
// 3 kernels:
//   prep  : weight transpose/bf16
//   fused : qkv-proj + attention + LePE per window (8 waves x 32 tokens),
//           writes per-head O (bf16) to workspace. NO out-proj accumulator ->
//           register state fits 128 VGPR (waves_per_eu(4,4), no spills).
//   oproj : O @ out_w^T + bias with reverse window partition (plain GEMM).
// ---------------------------------------------------------------------------

typedef __attribute__((ext_vector_type(8))) short bf16x8;
typedef __attribute__((ext_vector_type(4))) float f32x4;

#define MFMA(a, b, c) __builtin_amdgcn_mfma_f32_16x16x32_bf16(a, b, c, 0, 0, 0)

#if __has_builtin(__builtin_amdgcn_exp2f)
#define EXP2F(x) __builtin_amdgcn_exp2f(x)
#else
#define EXP2F(x) exp2f(x)
#endif

#define SCALE2 (0.20412414523193154f * 1.4426950408889634f)

// ws layout (bytes)
#define OFF_WT   0u           // ushort[288*96]   qkv_w^T bf16 (row=out-ch, k-contig)
#define OFF_B2   55296u       // float[288]       qkv bias (q entries pre-scaled)
#define OFF_WTO  56448u       // ushort[96*96]    out_w^T bf16 (+slack for lq=3 over-read)
#define OFF_OB   75904u       // ushort[131072*96] per-head attention output O (bf16)
// end ~25.3 MB

__device__ __forceinline__ unsigned short f2bf(float f) {
    union { float f; unsigned int u; } v; v.f = f;
    unsigned int u = v.u;
    return (unsigned short)((u + 0x7FFFu + ((u >> 16) & 1u)) >> 16);
}
__device__ __forceinline__ float bf2f(unsigned short h) {
    union { unsigned int u; float f; } v; v.u = ((unsigned int)h) << 16;
    return v.f;
}
__device__ __forceinline__ unsigned int pk2bf(float a, float b) {
#if __has_builtin(__builtin_amdgcn_cvt_pk_bf16_f32)
    auto p = __builtin_amdgcn_cvt_pk_bf16_f32(a, b);
    union { decltype(p) v; unsigned int u; } cv; cv.v = p;
    return cv.u;
#else
    return (unsigned int)f2bf(a) | ((unsigned int)f2bf(b) << 16);
#endif
}
__device__ __forceinline__ float frcp(float x) {
#if __has_builtin(__builtin_amdgcn_rcpf)
    return __builtin_amdgcn_rcpf(x);
#else
    return 1.0f / x;
#endif
}

// ---------------------------------------------------------------------------
// prep: transpose + bf16-cast weights, pre-scale q rows.
// ---------------------------------------------------------------------------
__global__ void prep_kernel(const float* __restrict__ qkv_w,
                            const float* __restrict__ qkv_b,
                            const float* __restrict__ out_w,
                            unsigned short* __restrict__ wt,
                            float* __restrict__ b2,
                            unsigned short* __restrict__ wto) {
    const int stride = gridDim.x * 256;
    int i0 = blockIdx.x * 256 + threadIdx.x;
    for (int i = i0; i < 288 * 96; i += stride) {
        const int c = i / 96, k = i % 96;
        float v = qkv_w[k * 288 + c];
        if ((c % 72) < 24) v *= SCALE2;
        wt[i] = f2bf(v);
    }
    for (int i = i0; i < 288; i += stride) {
        float v = qkv_b[i];
        if ((i % 72) < 24) v *= SCALE2;
        b2[i] = v;
    }
    for (int i = i0; i < 96 * 96; i += stride) {
        const int c = i / 96, k = i % 96;
        wto[i] = f2bf(out_w[k * 96 + c]);
    }
}

// ---------------------------------------------------------------------------
// Fused kernel: 1 block per window (grid 512), 512 threads (8 waves).
// Wave w owns tokens w*32..w*32+31 (token tiles w*2, w*2+1).
// LDS: ~49.5 KB -> 2 blocks/CU = 16 waves/CU (pinned via waves_per_eu(4,4)).
// ---------------------------------------------------------------------------
__global__ __launch_bounds__(512) __attribute__((amdgpu_waves_per_eu(4, 4)))
void fused_kernel(const float* __restrict__ x,
                  const unsigned short* __restrict__ wt,
                  const float* __restrict__ b2,
                  const float* __restrict__ pe_w,
                  const float* __restrict__ pe_b,
                  unsigned short* __restrict__ Ob) {
    __shared__ unsigned short sK[256 * 24 + 8];     // 12304 B shared K (token-major)
    __shared__ unsigned short sVT[32 * 264];        // 16896 B V^T; row24=ones, 25..31 junk (contained)
    __shared__ unsigned short sPO[8 * 32 * 40];     // 20480 B per-wave Q / P overlay
    __shared__ float sPW[216];
    __shared__ float sPB[24];

    const int n = blockIdx.x, tid = threadIdx.x;
    const int w = tid >> 6, l = tid & 63;
    const int lm = l & 15, lq = l >> 4;
    const int bW = n >> 8, hy = (n >> 4) & 15, wx = n & 15;
    unsigned short* Pw = &sPO[w * 32 * 40];

    // ones row of sVT (denominator column), written once
    if (tid < 64) {
        ushort4 ones; ones.x = ones.y = ones.z = ones.w = (unsigned short)0x3F80;
        *(ushort4*)&sVT[24 * 264 + tid * 4] = ones;
    }

    // ---- x fragments for this wave's 2 token tiles, held in registers ----
    // token = w*32 + t4*16 + lm  ->  y = w*2 + t4, x = lm  (within window)
    bf16x8 zf[2][3];
#pragma unroll
    for (int t4 = 0; t4 < 2; t4++) {
        const int y = w * 2 + t4;
        const size_t grow = (size_t)((bW * 256 + hy * 16 + y) * 256 + wx * 16 + lm);
        const float* xr = x + grow * 96 + lq * 8;
#pragma unroll
        for (int ks = 0; ks < 3; ks++) {
            const float4 p0 = *(const float4*)(xr + ks * 32);
            const float4 p1 = *(const float4*)(xr + ks * 32 + 4);
            union { unsigned int u[4]; bf16x8 v; } cv;
            cv.u[0] = pk2bf(p0.x, p0.y); cv.u[1] = pk2bf(p0.z, p0.w);
            cv.u[2] = pk2bf(p1.x, p1.y); cv.u[3] = pk2bf(p1.z, p1.w);
            zf[t4][ks] = cv.v;
        }
    }

    for (int h = 0; h < 4; h++) {
        __syncthreads();   // prev head's sK/sVT/sPW readers done

        // ---- Phase A: Q,K head h for this wave's tokens (out-ch rows of wt) ----
        // Output: col=lm -> token (w*32 + t4*16 + lm), row=r48=mt*16+lq*4 -> qkv ch.
        // r48<24 -> Q (wave-private overlay, pitch 40), else K (shared, pitch 24).
#pragma unroll
        for (int mt = 0; mt < 3; mt++) {
            bf16x8 af[3];
#pragma unroll
            for (int ks = 0; ks < 3; ks++)
                af[ks] = *(const bf16x8*)(wt + (h * 72 + mt * 16 + lm) * 96 + ks * 32 + lq * 8);
            const int r48 = mt * 16 + lq * 4;
            const float4 bias = *(const float4*)(b2 + h * 72 + r48);
#pragma unroll
            for (int t4 = 0; t4 < 2; t4++) {
                f32x4 acc = {0.f, 0.f, 0.f, 0.f};
#pragma unroll
                for (int ks = 0; ks < 3; ks++) acc = MFMA(af[ks], zf[t4][ks], acc);
                uint2 pk;
                pk.x = pk2bf(acc[0] + bias.x, acc[1] + bias.y);
                pk.y = pk2bf(acc[2] + bias.z, acc[3] + bias.w);
                const int tl = t4 * 16 + lm;           // local token 0..31
                if (r48 < 24) *(uint2*)&Pw[tl * 40 + r48] = pk;
                else          *(uint2*)&sK[(w * 32 + tl) * 24 + (r48 - 24)] = pk;
            }
        }

        // ---- Phase B: V^T head h for this wave's tokens ----
#pragma unroll
        for (int nv = 0; nv < 2; nv++) {
            const int ch = nv * 16 + lm;
            const int vrow = h * 72 + 48 + (ch < 24 ? ch : 23);
            bf16x8 bw[3];
#pragma unroll
            for (int ks = 0; ks < 3; ks++)
                bw[ks] = *(const bf16x8*)(wt + vrow * 96 + ks * 32 + lq * 8);
            const float bv = b2[vrow];
#pragma unroll
            for (int t4 = 0; t4 < 2; t4++) {
                f32x4 acc = {0.f, 0.f, 0.f, 0.f};
#pragma unroll
                for (int ks = 0; ks < 3; ks++) acc = MFMA(zf[t4][ks], bw[ks], acc);
                if (ch < 24) {
                    uint2 pk;
                    pk.x = pk2bf(acc[0] + bv, acc[1] + bv);
                    pk.y = pk2bf(acc[2] + bv, acc[3] + bv);
                    *(uint2*)&sVT[ch * 264 + w * 32 + t4 * 16 + lq * 4] = pk;
                }
            }
        }

        // LePE weights for head h
        for (int i = tid; i < 216; i += 512) sPW[i] = pe_w[(i / 24) * 96 + h * 24 + (i % 24)];
        if (tid < 24) sPB[tid] = pe_b[h * 24 + tid];

        __syncthreads();   // K / V^T / pe staged

        // ---- attention (all operands in LDS) ----
        // Q consumed into registers BEFORE first P write to the same region
        // (wave-private, DS in-order per wave => safe overlay).
        bf16x8 qf[2];
#pragma unroll
        for (int b = 0; b < 2; b++) {
            bf16x8 qv = *(const bf16x8*)&Pw[(b * 16 + lm) * 40 + lq * 8];
            if (lq == 3) qv = (bf16x8)(short)0;
            qf[b] = qv;
        }

        f32x4 oa[2][2];
#pragma unroll
        for (int b = 0; b < 2; b++)
#pragma unroll
            for (int c = 0; c < 2; c++) oa[b][c] = (f32x4){0.f, 0.f, 0.f, 0.f};

        for (int kc = 0; kc < 8; kc++) {
            bf16x8 kfc[2];
#pragma unroll
            for (int a = 0; a < 2; a++)
                kfc[a] = *(const bf16x8*)&sK[(kc * 32 + a * 16 + lm) * 24 + lq * 8];
#pragma unroll
            for (int a = 0; a < 2; a++) {
                f32x4 s[2];
#pragma unroll
                for (int b = 0; b < 2; b++)
                    s[b] = MFMA(kfc[a], qf[b], ((f32x4){0.f, 0.f, 0.f, 0.f}));
#pragma unroll
                for (int b = 0; b < 2; b++) {
                    uint2 pk;
                    pk.x = pk2bf(EXP2F(s[b][0]), EXP2F(s[b][1]));
                    pk.y = pk2bf(EXP2F(s[b][2]), EXP2F(s[b][3]));
                    *(uint2*)&Pw[(b * 16 + lm) * 40 + a * 16 + lq * 4] = pk;
                }
            }
            bf16x8 vb[2];
#pragma unroll
            for (int c = 0; c < 2; c++)
                vb[c] = *(const bf16x8*)&sVT[(c * 16 + lm) * 264 + kc * 32 + lq * 8];
#pragma unroll
            for (int b = 0; b < 2; b++) {
                const bf16x8 pa = *(const bf16x8*)&Pw[(b * 16 + lm) * 40 + lq * 8];
#pragma unroll
                for (int c = 0; c < 2; c++) oa[b][c] = MFMA(pa, vb[c], oa[b][c]);
            }
        }

        // ---- epilogue: denom, LePE (strip reads), O -> global (bf16) ----
        float w9[2][9], pb2[2];
#pragma unroll
        for (int c = 0; c < 2; c++) {
            const int ch = c * 16 + lm;
            if (ch < 24) {
#pragma unroll
                for (int ta = 0; ta < 9; ta++) w9[c][ta] = sPW[ta * 24 + ch];
                pb2[c] = sPB[ch];
            }
        }
#pragma unroll
        for (int b = 0; b < 2; b++) {
            float rinv[4];
#pragma unroll
            for (int r = 0; r < 4; r++)
                rinv[r] = frcp(__shfl(oa[b][1][r], (l & 48) | 8, 64));
            const int y = w * 2 + b;     // all 16 tokens of this m-tile share y
            const int x0 = lq * 4;
#pragma unroll
            for (int c = 0; c < 2; c++) {
                const int ch = c * 16 + lm;
                if (ch < 24) {
                    float lep[4] = {pb2[c], pb2[c], pb2[c], pb2[c]};
                    const unsigned short* vbase = &sVT[ch * 264];
#pragma unroll
                    for (int dy = -1; dy <= 1; dy++) {
                        const int ny = y + dy;
                        if ((unsigned)ny > 15u) continue;
                        const unsigned short* vrow = vbase + ny * 16;
                        const float wl = w9[c][(dy + 1) * 3 + 0];
                        const float wm = w9[c][(dy + 1) * 3 + 1];
                        const float wr = w9[c][(dy + 1) * 3 + 2];
#pragma unroll
                        for (int d = -1; d <= 4; d++) {
                            const int xx = x0 + d;
                            if ((unsigned)xx > 15u) continue;
                            const float v = bf2f(vrow[xx]);
                            if (d - 1 >= 0 && d - 1 <= 3) lep[d - 1] = fmaf(v, wr, lep[d - 1]);
                            if (d >= 0 && d <= 3)         lep[d]     = fmaf(v, wm, lep[d]);
                            if (d + 1 <= 3)               lep[d + 1] = fmaf(v, wl, lep[d + 1]);
                        }
                    }
#pragma unroll
                    for (int r = 0; r < 4; r++) {
                        const float val = oa[b][c][r] * rinv[r] + lep[r];
                        const size_t gtok = (size_t)n * 256 + w * 32 + b * 16 + lq * 4 + r;
                        Ob[gtok * 96 + h * 24 + ch] = f2bf(val);
                    }
                }
            }
        }
    }
}

// ---------------------------------------------------------------------------
// oproj: out = O @ out_w^T + bias, with reverse window partition store.
// 1024 blocks x 256 threads; wave owns 32 tokens; K=96 contraction.
// ---------------------------------------------------------------------------
__global__ __launch_bounds__(256) __attribute__((amdgpu_waves_per_eu(4, 4)))
void oproj_kernel(const unsigned short* __restrict__ Ob,
                  const unsigned short* __restrict__ wto,
                  const float* __restrict__ out_b,
                  float* __restrict__ out) {
    const int chunk = blockIdx.x, tid = threadIdx.x;
    const int w = tid >> 6, l = tid & 63;
    const int lm = l & 15, lq = l >> 4;
    const int n = chunk >> 1;
    const int T0 = (chunk & 1) << 7;
    const int bW = n >> 8, hy = (n >> 4) & 15, wx = n & 15;
    const int tb = T0 + w * 32;                 // local token base of this wave
    const size_t gb = (size_t)n * 256 + tb;     // global token base

    // A fragments: O rows (token-major, k = 96 channels)
    bf16x8 aO[2][3];
#pragma unroll
    for (int b = 0; b < 2; b++)
#pragma unroll
        for (int ks = 0; ks < 3; ks++)
            aO[b][ks] = *(const bf16x8*)(Ob + (gb + b * 16 + lm) * 96 + ks * 32 + lq * 8);

    f32x4 acc[2][6];
#pragma unroll
    for (int b = 0; b < 2; b++)
#pragma unroll
        for (int nt = 0; nt < 6; nt++) acc[b][nt] = (f32x4){0.f, 0.f, 0.f, 0.f};

#pragma unroll
    for (int nt = 0; nt < 6; nt++) {
#pragma unroll
        for (int ks = 0; ks < 3; ks++) {
            const bf16x8 bw = *(const bf16x8*)(wto + (nt * 16 + lm) * 96 + ks * 32 + lq * 8);
#pragma unroll
            for (int b = 0; b < 2; b++) acc[b][nt] = MFMA(aO[b][ks], bw, acc[b][nt]);
        }
    }

    // store with reverse window partition
#pragma unroll
    for (int nt = 0; nt < 6; nt++) {
        const float bias = out_b[nt * 16 + lm];
#pragma unroll
        for (int b = 0; b < 2; b++) {
#pragma unroll
            for (int r = 0; r < 4; r++) {
                const int t = tb + b * 16 + lq * 4 + r;
                const size_t grow =
                    (size_t)((bW * 256 + hy * 16 + (t >> 4)) * 256 + wx * 16 + (t & 15));
                out[grow * 96 + nt * 16 + lm] = acc[b][nt][r] + bias;
            }
        }
    }
}

extern "C" void kernel_launch(void* const* d_in, const int* in_sizes, int n_in,
                              void* d_out, int out_size, void* d_ws, size_t ws_size,
                              hipStream_t stream) {
    const float* x     = (const float*)d_in[0];
    const float* qkv_w = (const float*)d_in[1];
    const float* qkv_b = (const float*)d_in[2];
    const float* pe_w  = (const float*)d_in[3];
    const float* pe_b  = (const float*)d_in[4];
    const float* out_w = (const float*)d_in[5];
    const float* out_b = (const float*)d_in[6];
    float* out = (float*)d_out;

    char* ws = (char*)d_ws;
    unsigned short* wt  = (unsigned short*)(ws + OFF_WT);
    float*          b2  = (float*)(ws + OFF_B2);
    unsigned short* wto = (unsigned short*)(ws + OFF_WTO);
    unsigned short* Ob  = (unsigned short*)(ws + OFF_OB);

    prep_kernel<<<72, 256, 0, stream>>>(qkv_w, qkv_b, out_w, wt, b2, wto);
    fused_kernel<<<512, 512, 0, stream>>>(x, wt, b2, pe_w, pe_b, Ob);
    oproj_kernel<<<1024, 256, 0, stream>>>(Ob, wto, out_b, out);
}